// Round 5
// baseline (114.411 us; speedup 1.0000x reference)
//
#include <hip/hip_runtime.h>
#include <stdint.h>

#define LOG2E 1.4426950408889634f

typedef __attribute__((ext_vector_type(8))) __bf16 bf16x8;
typedef __attribute__((ext_vector_type(4))) __bf16 bf16x4;
typedef __attribute__((ext_vector_type(4))) float f32x4;

__device__ inline void gll16(const void* g, void* l) {
  __builtin_amdgcn_global_load_lds(
      (const __attribute__((address_space(1))) void*)g,
      (__attribute__((address_space(3))) void*)l, 16, 0, 0);
}

// ---------------- fp32 -> bf16 conversion (all 5 tensors, one launch) ----------------
__global__ __launch_bounds__(256) void cvt_all(
    const float* __restrict__ hs, const float* __restrict__ wq,
    const float* __restrict__ wk, const float* __restrict__ wv,
    const float* __restrict__ wo,
    __bf16* __restrict__ hsb, __bf16* __restrict__ wqb, __bf16* __restrict__ wkb,
    __bf16* __restrict__ wvb, __bf16* __restrict__ wob) {
  int bid = blockIdx.x;
  const float* s; __bf16* d; int i;
  if (bid < 4096) { s = hs; d = hsb; i = bid * 256 + threadIdx.x; }
  else {
    int seg = (bid - 4096) >> 10;
    i = ((bid - 4096) & 1023) * 256 + threadIdx.x;
    s = seg == 0 ? wq : seg == 1 ? wk : seg == 2 ? wv : wo;
    d = seg == 0 ? wqb : seg == 1 ? wkb : seg == 2 ? wvb : wob;
  }
  float4 v = ((const float4*)s)[i];
  bf16x4 o;
  o[0] = (__bf16)v.x; o[1] = (__bf16)v.y; o[2] = (__bf16)v.z; o[3] = (__bf16)v.w;
  *(bf16x4*)&d[(size_t)i * 4] = o;
}

// ---------------- merged QKV projection GEMM (unchanged) ----------------
#define KSCALE 0.18033688011112042f  // HD^-0.5 * log2(e)
__global__ __launch_bounds__(256, 3) void qkv_gemm(
    const __bf16* __restrict__ hsb, const __bf16* __restrict__ wqb,
    const __bf16* __restrict__ wkb, const __bf16* __restrict__ wvb,
    __bf16* __restrict__ qbuf, __bf16* __restrict__ kbuf,
    __bf16* __restrict__ vtb) {
  constexpr int K = 1024;
  __shared__ __align__(16) __bf16 lta[128 * 32];
  __shared__ __align__(16) __bf16 ltb[128 * 32];
  const int bid = blockIdx.x;
  const int z = bid >> 8, r = bid & 255;
  const __bf16 *A, *Bt;
  int m0, n0;
  if (z < 2) {
    A = hsb; Bt = z ? wkb : wqb;
    m0 = (r & 31) * 128; n0 = (r >> 5) * 128;
  } else {
    A = wvb; Bt = hsb;
    m0 = (r & 7) * 128; n0 = (r >> 3) * 128;
  }
  const int tid = threadIdx.x;
  const int w = tid >> 6, l = tid & 63;
  const int lg = l >> 4, lr = l & 15;
  const int wm = (w >> 1) * 64, wn = (w & 1) * 64;
  f32x4 acc[4][4] = {};
  const int srow = w * 16 + (l >> 2);
  const int scol = (l & 3) * 8;
  const __bf16* ga = A + (size_t)(m0 + srow) * K + scol;
  const __bf16* gb = Bt + (size_t)(n0 + srow) * K + scol;
  __bf16* la = &lta[(size_t)w * 16 * 32];
  __bf16* lb = &ltb[(size_t)w * 16 * 32];
  for (int k0 = 0; k0 < K; k0 += 32) {
    __syncthreads();
    gll16(ga + k0, la);
    gll16(ga + 64 * K + k0, la + 64 * 32);
    gll16(gb + k0, lb);
    gll16(gb + 64 * K + k0, lb + 64 * 32);
    __syncthreads();
    bf16x8 af[4], bfr[4];
#pragma unroll
    for (int i = 0; i < 4; ++i) {
      af[i]  = *(const bf16x8*)&lta[(wm + i * 16 + lr) * 32 + lg * 8];
      bfr[i] = *(const bf16x8*)&ltb[(wn + i * 16 + lr) * 32 + lg * 8];
    }
#pragma unroll
    for (int i = 0; i < 4; ++i)
#pragma unroll
      for (int j = 0; j < 4; ++j)
        acc[i][j] = __builtin_amdgcn_mfma_f32_16x16x32_bf16(af[i], bfr[j], acc[i][j], 0, 0, 0);
  }
#pragma unroll
  for (int i = 0; i < 4; ++i)
#pragma unroll
    for (int j = 0; j < 4; ++j)
#pragma unroll
      for (int rr = 0; rr < 4; ++rr) {
        int gm = m0 + wm + i * 16 + lg * 4 + rr;
        int gn = n0 + wn + j * 16 + lr;
        float v = acc[i][j][rr];
        if (z < 2) {
          int bb = gm >> 11, s = gm & 2047, hh = gn >> 6, d = gn & 63;
          __bf16* dst = z ? kbuf : qbuf;
          if (z) v *= KSCALE;
          dst[(((size_t)bb * 16 + hh) * 2048 + s) * 64 + d] = (__bf16)v;
        } else {
          int bb = gn >> 11, s = gn & 2047, hh = gm >> 6, d = gm & 63;
          vtb[(((size_t)bb * 16 + hh) * 64 + d) * 2048 + s] = (__bf16)v;
        }
      }
}

// ---------------- output GEMM: 128x64 tiles -> 512 blocks (2/CU) ----------------
__global__ __launch_bounds__(256, 2) void gemm_out(const __bf16* __restrict__ A,
                                                   const __bf16* __restrict__ Bt,
                                                   float* __restrict__ C,
                                                   int M, int N) {
  constexpr int K = 1024;
  __shared__ __align__(16) __bf16 lta[128 * 32];
  __shared__ __align__(16) __bf16 ltb[64 * 32];
  const int tid = threadIdx.x;
  const int w = tid >> 6, l = tid & 63;
  const int lg = l >> 4, lr = l & 15;
  const int m0 = blockIdx.x * 128, n0 = blockIdx.y * 64;
  const int wm = (w >> 1) * 64, wn = (w & 1) * 32;
  f32x4 acc[4][2] = {};
  const int srow = tid >> 2;          // 0..63
  const int scol = (tid & 3) * 8;
  const __bf16* ga = A + (size_t)(m0 + srow) * K + scol;
  const __bf16* gb = Bt + (size_t)(n0 + srow) * K + scol;
  __bf16* la = &lta[(size_t)w * 512];
  __bf16* lb = &ltb[(size_t)w * 512];
  for (int k0 = 0; k0 < K; k0 += 32) {
    __syncthreads();
    gll16(ga + k0, la);
    gll16(ga + (size_t)64 * K + k0, la + 64 * 32);
    gll16(gb + k0, lb);
    __syncthreads();
    bf16x8 af[4], bfr[2];
#pragma unroll
    for (int i = 0; i < 4; ++i)
      af[i]  = *(const bf16x8*)&lta[(wm + i * 16 + lr) * 32 + lg * 8];
#pragma unroll
    for (int j = 0; j < 2; ++j)
      bfr[j] = *(const bf16x8*)&ltb[(wn + j * 16 + lr) * 32 + lg * 8];
#pragma unroll
    for (int i = 0; i < 4; ++i)
#pragma unroll
      for (int j = 0; j < 2; ++j)
        acc[i][j] = __builtin_amdgcn_mfma_f32_16x16x32_bf16(af[i], bfr[j], acc[i][j], 0, 0, 0);
  }
#pragma unroll
  for (int i = 0; i < 4; ++i)
#pragma unroll
    for (int j = 0; j < 2; ++j)
#pragma unroll
      for (int rr = 0; rr < 4; ++rr) {
        int gm = m0 + wm + i * 16 + lg * 4 + rr;
        int gn = n0 + wn + j * 16 + lr;
        C[(size_t)gm * N + gn] = acc[i][j][rr];
      }
}

// ---------------- attention + memory retrieval ----------------
// 1024 blocks: t = 31-(bx>>5) (big-first), bh = bx&31. 4 waves = 2 KV-split
// pairs: wave w: qh = w&1 (q rows t*64+qh*32 .. +31, mf=2 sub-blocks of 16),
// par = w>>1 (pair 0: KV tiles [0,cA), pair 1: [cA,nt)). Private kt/vt per
// pair; flash states merged via LDS at the end. Swapped QK^T, per-lane q=lr
// softmax in exp2 domain (K pre-scaled). XOR-swizzled LDS.
#define DEFER_THR 11.5f
#define SWZ(row, col) (((row) << 7) + ((col) ^ (((row) & 7) << 3)))   // stride 128
#define SWZK(row, col) (((row) << 6) + ((col) ^ (((row) & 7) << 3)))  // stride 64

__global__ __launch_bounds__(256, 2) void attn_kernel(
    const __bf16* __restrict__ qb,    // [32][2048][64]
    const __bf16* __restrict__ kb,    // [32][2048][64] (pre-scaled)
    const __bf16* __restrict__ vtb,   // [32][64][2048]
    const float* __restrict__ memory, // [16][64][64]
    const float* __restrict__ memnorm,// [16][64]
    const float* __restrict__ beta,   // [16]
    __bf16* __restrict__ comb)        // [4096][1024]
{
  __shared__ __align__(16) __bf16 kt[2][128 * 64];  // 32 KB (epilogue: dumpO + mt)
  __shared__ __align__(16) __bf16 vt[2][64 * 128];  // 32 KB (epilogue: dumpML)
  __shared__ __align__(16) __bf16 pt[4][16 * 128];  // 16 KB  -> 80 KB total

  const int tid = threadIdx.x;
  const int w = tid >> 6, l = tid & 63;
  const int lg = l >> 4, lr = l & 15;
  const int qh = w & 1, par = w >> 1;
  const int ltid = tid & 127;
  const int t = 31 - (blockIdx.x >> 5);
  const int bh = blockIdx.x & 31;
  const int hh = bh & 15, b = bh >> 4;
  const int wq0 = t * 64 + qh * 32;
  const int nt = (t >> 1) + 1;
  const int cA = (nt + 1) >> 1;
  const int cnt = par ? (nt - cA) : cA;
  const int kvbase = par ? cA * 128 : 0;

  // staging coords (per pair: 128 threads stage one 128x64 K tile + 64x128 V^T tile)
  const int s_sk = ltid >> 3, s_d8 = (ltid & 7) * 8;
  const int s_d = ltid >> 4, s_sk8 = (ltid & 15) * 8;
  const __bf16* kbase = kb + ((size_t)bh * 2048 + kvbase + s_sk) * 64 + s_d8;
  const __bf16* vbase = vtb + ((size_t)bh * 64 + s_d) * 2048 + kvbase + s_sk8;

  // ---- Q fragments (per-lane: row/col = lr; mf picks 16-row sub-block) ----
  bf16x8 qf[2][2];
#pragma unroll
  for (int mf = 0; mf < 2; ++mf)
#pragma unroll
    for (int kk = 0; kk < 2; ++kk)
      qf[mf][kk] = *(const bf16x8*)(qb + ((size_t)bh * 2048 + wq0 + mf * 16 + lr) * 64 + kk * 32 + lg * 8);

  // ---- prologue loads ----
  bf16x8 kst[8], vst[8];
  if (cnt > 0) {
#pragma unroll
    for (int i = 0; i < 8; ++i) {
      kst[i] = *(const bf16x8*)(kbase + i * 1024);
      vst[i] = *(const bf16x8*)(vbase + (size_t)i * 16384);
    }
  }

  float mrun[2] = {-1e30f, -1e30f}, lsum[2] = {0.f, 0.f};
  f32x4 apv[2][4] = {};

  for (int kv = 0; kv < cA; ++kv) {
    const bool vcur = kv < cnt;
    __syncthreads();
    if (vcur) {
#pragma unroll
      for (int i = 0; i < 8; ++i) {
        *(bf16x8*)&kt[par][SWZK(s_sk + i * 16, s_d8)] = kst[i];
        *(bf16x8*)&vt[par][SWZ(s_d + i * 8, s_sk8)] = vst[i];
      }
    }
    __syncthreads();
    if (kv + 1 < cnt) {
#pragma unroll
      for (int i = 0; i < 8; ++i) {
        kst[i] = *(const bf16x8*)(kbase + (size_t)(kv + 1) * 8192 + i * 1024);
        vst[i] = *(const bf16x8*)(vbase + (kv + 1) * 128 + (size_t)i * 16384);
      }
    }
    if (!vcur) continue;
    const int kv0 = kvbase + kv * 128;

    // ---- QK^T swapped: sc[mf][nf]: k = kv0+nf*16+lg*4+r, q = wq0+mf*16+lr ----
    f32x4 sc[2][8] = {};
#pragma unroll
    for (int kk = 0; kk < 2; ++kk)
#pragma unroll
      for (int nf = 0; nf < 8; ++nf) {
        bf16x8 kf = *(const bf16x8*)&kt[par][SWZK(nf * 16 + lr, kk * 32 + lg * 8)];
#pragma unroll
        for (int mf = 0; mf < 2; ++mf)
          sc[mf][nf] = __builtin_amdgcn_mfma_f32_16x16x32_bf16(kf, qf[mf][kk], sc[mf][nf], 0, 0, 0);
      }

    // ---- causal mask ----
    if (kv0 + 127 > wq0) {
#pragma unroll
      for (int mf = 0; mf < 2; ++mf) {
        const int qrow = wq0 + mf * 16 + lr;
#pragma unroll
        for (int nf = 0; nf < 8; ++nf)
#pragma unroll
          for (int r = 0; r < 4; ++r)
            if (kv0 + nf * 16 + lg * 4 + r > qrow) sc[mf][nf][r] = -1e30f;
      }
    }

    // ---- per-mf max + defer rescale ----
#pragma unroll
    for (int mf = 0; mf < 2; ++mf) {
      f32x4 m4 = sc[mf][0];
#pragma unroll
      for (int nf = 1; nf < 8; ++nf)
#pragma unroll
        for (int r = 0; r < 4; ++r) m4[r] = fmaxf(m4[r], sc[mf][nf][r]);
      float mx = fmaxf(fmaxf(m4[0], m4[1]), fmaxf(m4[2], m4[3]));
      mx = fmaxf(mx, __shfl_xor(mx, 16, 64));
      mx = fmaxf(mx, __shfl_xor(mx, 32, 64));
      if (!__all(mx - mrun[mf] <= DEFER_THR)) {
        float mold = mrun[mf];
        float mn = fmaxf(mold, mx);
        mrun[mf] = mn;
        float scl = __builtin_amdgcn_exp2f(mold - mn);
        lsum[mf] *= scl;
        float sclq[4];
#pragma unroll
        for (int r = 0; r < 4; ++r) sclq[r] = __shfl(scl, (lg << 2) | r, 16);
#pragma unroll
        for (int nf = 0; nf < 4; ++nf)
#pragma unroll
          for (int r = 0; r < 4; ++r) apv[mf][nf][r] *= sclq[r];
      }
    }

    // ---- P(mf=0) -> pt, cache pa0 in regs; then P(mf=1) -> pt ----
    bf16x8 pa0[4];
    {
      float rs = 0.f;
#pragma unroll
      for (int nf = 0; nf < 8; ++nf) {
        bf16x4 pk;
#pragma unroll
        for (int r = 0; r < 4; ++r) {
          float pv = __builtin_amdgcn_exp2f(sc[0][nf][r] - mrun[0]);
          rs += pv;
          pk[r] = (__bf16)pv;
        }
        *(bf16x4*)&pt[w][SWZ(lr, nf * 16 + lg * 4)] = pk;
      }
      rs += __shfl_xor(rs, 16, 64);
      rs += __shfl_xor(rs, 32, 64);
      lsum[0] += rs;
#pragma unroll
      for (int kk = 0; kk < 4; ++kk)
        pa0[kk] = *(const bf16x8*)&pt[w][SWZ(lr, kk * 32 + lg * 8)];
    }
    {
      float rs = 0.f;
#pragma unroll
      for (int nf = 0; nf < 8; ++nf) {
        bf16x4 pk;
#pragma unroll
        for (int r = 0; r < 4; ++r) {
          float pv = __builtin_amdgcn_exp2f(sc[1][nf][r] - mrun[1]);
          rs += pv;
          pk[r] = (__bf16)pv;
        }
        *(bf16x4*)&pt[w][SWZ(lr, nf * 16 + lg * 4)] = pk;
      }
      rs += __shfl_xor(rs, 16, 64);
      rs += __shfl_xor(rs, 32, 64);
      lsum[1] += rs;
    }

    // ---- PV: V-frags read once, feed both mf ----
#pragma unroll
    for (int kk = 0; kk < 4; ++kk) {
      bf16x8 pa1 = *(const bf16x8*)&pt[w][SWZ(lr, kk * 32 + lg * 8)];
#pragma unroll
      for (int nf = 0; nf < 4; ++nf) {
        bf16x8 vf = *(const bf16x8*)&vt[par][SWZ(nf * 16 + lr, kk * 32 + lg * 8)];
        apv[0][nf] = __builtin_amdgcn_mfma_f32_16x16x32_bf16(pa0[kk], vf, apv[0][nf], 0, 0, 0);
        apv[1][nf] = __builtin_amdgcn_mfma_f32_16x16x32_bf16(pa1, vf, apv[1][nf], 0, 0, 0);
      }
    }
  }

  // ---- merge pair states + memory term + write ----
  __syncthreads();
  float* dumpO  = (float*)&kt[0][0];   // [qh][32 q][64 d]
  float* dumpML = (float*)&vt[0][0];   // m: [0..127], l: [128..255]
  __bf16* mt = &kt[1][0];              // memory^T [80][72]
  if (par == 1) {
#pragma unroll
    for (int mf = 0; mf < 2; ++mf) {
#pragma unroll
      for (int nf = 0; nf < 4; ++nf)
#pragma unroll
        for (int r = 0; r < 4; ++r)
          dumpO[qh * 2048 + (mf * 16 + lg * 4 + r) * 64 + nf * 16 + lr] = apv[mf][nf][r];
      dumpML[qh * 64 + mf * 16 + lr] = mrun[mf];
      dumpML[128 + qh * 64 + mf * 16 + lr] = lsum[mf];
    }
  } else {
    for (int i = tid; i < 64 * 64; i += 128) {
      int d = i >> 6, e = i & 63;
      mt[e * 72 + d] = (__bf16)memory[((size_t)hh * 64 + d) * 64 + e];
    }
    for (int i = tid; i < 16 * 64; i += 128) {
      int e = 64 + (i >> 6), d = i & 63;
      mt[e * 72 + d] = (__bf16)memnorm[hh * 64 + d];
    }
  }
  __syncthreads();
  if (par == 1) return;

  // flash-merge (pair 0 absorbs pair 1)
  float lq[2][4], f1v[2], f2v[2];
#pragma unroll
  for (int mf = 0; mf < 2; ++mf) {
    float m2 = dumpML[qh * 64 + mf * 16 + lr];
    float l2 = dumpML[128 + qh * 64 + mf * 16 + lr];
    float m1 = mrun[mf];
    float fm = fmaxf(m1, m2);
    f1v[mf] = __builtin_amdgcn_exp2f(m1 - fm);
    f2v[mf] = __builtin_amdgcn_exp2f(m2 - fm);
    float lm = f1v[mf] * lsum[mf] + f2v[mf] * l2;
#pragma unroll
    for (int r = 0; r < 4; ++r) lq[mf][r] = __shfl(lm, (lg << 2) | r, 16);
  }
#pragma unroll
  for (int mf = 0; mf < 2; ++mf)
#pragma unroll
    for (int r = 0; r < 4; ++r) {
      float f1q = __shfl(f1v[mf], (lg << 2) | r, 16);
      float f2q = __shfl(f2v[mf], (lg << 2) | r, 16);
#pragma unroll
      for (int nf = 0; nf < 4; ++nf) {
        float o2 = dumpO[qh * 2048 + (mf * 16 + lg * 4 + r) * 64 + nf * 16 + lr];
        apv[mf][nf][r] = f1q * apv[mf][nf][r] + f2q * o2;
      }
    }

  // sigma(Q) @ [M^T | norm]
  bf16x8 sf[2][2];
#pragma unroll
  for (int mf = 0; mf < 2; ++mf)
#pragma unroll
    for (int kk = 0; kk < 2; ++kk) {
      bf16x8 q = qf[mf][kk], s;
#pragma unroll
      for (int j = 0; j < 8; ++j) {
        float x = (float)q[j];
        float sg = x > 0.f ? x + 1.f : __builtin_amdgcn_exp2f(x * LOG2E);
        s[j] = (__bf16)sg;
      }
      sf[mf][kk] = s;
    }
  f32x4 am[2][5] = {};
#pragma unroll
  for (int kk = 0; kk < 2; ++kk)
#pragma unroll
    for (int nf = 0; nf < 5; ++nf) {
      bf16x8 bb = *(const bf16x8*)&mt[(nf * 16 + lr) * 72 + kk * 32 + lg * 8];
#pragma unroll
      for (int mf = 0; mf < 2; ++mf)
        am[mf][nf] = __builtin_amdgcn_mfma_f32_16x16x32_bf16(sf[mf][kk], bb, am[mf][nf], 0, 0, 0);
    }

  const float gate = 1.f / (1.f + __builtin_amdgcn_exp2f(-beta[hh] * LOG2E));
  const float og = 1.f - gate;
#pragma unroll
  for (int mf = 0; mf < 2; ++mf)
#pragma unroll
    for (int r = 0; r < 4; ++r) {
      int row = wq0 + mf * 16 + lg * 4 + r;
      float linv = __builtin_amdgcn_rcpf(lq[mf][r]);
      float nrm = fmaxf(am[mf][4][r], 1e-6f);
      float ninv = __builtin_amdgcn_rcpf(nrm);
      size_t base = ((size_t)b * 2048 + row) * 1024 + hh * 64;
#pragma unroll
      for (int nf = 0; nf < 4; ++nf)
        comb[base + nf * 16 + lr] =
            (__bf16)(gate * am[mf][nf][r] * ninv + og * apv[mf][nf][r] * linv);
    }
}

// ---------------- launch ----------------
extern "C" void kernel_launch(void* const* d_in, const int* in_sizes, int n_in,
                              void* d_out, int out_size, void* d_ws, size_t ws_size,
                              hipStream_t stream) {
  const float* hs      = (const float*)d_in[0];
  const float* wq      = (const float*)d_in[1];
  const float* wk      = (const float*)d_in[2];
  const float* wv      = (const float*)d_in[3];
  const float* wo      = (const float*)d_in[4];
  const float* beta    = (const float*)d_in[5];
  const float* memory  = (const float*)d_in[6];
  const float* memnorm = (const float*)d_in[7];
  float* out = (float*)d_out;

  char* ws = (char*)d_ws;
  __bf16* hsb  = (__bf16*)(ws);                        // 8 MB  [4096][1024]
  __bf16* wqb  = (__bf16*)(ws + ((size_t)8  << 20));   // 2 MB
  __bf16* wkb  = (__bf16*)(ws + ((size_t)10 << 20));   // 2 MB
  __bf16* wvb  = (__bf16*)(ws + ((size_t)12 << 20));   // 2 MB
  __bf16* wob  = (__bf16*)(ws + ((size_t)14 << 20));   // 2 MB
  __bf16* qbuf = (__bf16*)(ws + ((size_t)16 << 20));   // 8 MB  [32][2048][64]
  __bf16* kbuf = (__bf16*)(ws + ((size_t)24 << 20));   // 8 MB
  __bf16* vtb  = (__bf16*)(ws + ((size_t)32 << 20));   // 8 MB  [32][64][2048]
  __bf16* comb = (__bf16*)(ws + ((size_t)40 << 20));   // 8 MB  [4096][1024]

  cvt_all<<<8192, 256, 0, stream>>>(hs, wq, wk, wv, wo, hsb, wqb, wkb, wvb, wob);

  qkv_gemm<<<768, 256, 0, stream>>>(hsb, wqb, wkb, wvb, qbuf, kbuf, vtb);

  attn_kernel<<<1024, 256, 0, stream>>>(qbuf, kbuf, vtb, memory, memnorm, beta, comb);

  gemm_out<<<dim3(32, 16), 256, 0, stream>>>(comb, wob, out, 4096, 1024);
}

// Round 6
// 110.373 us; speedup vs baseline: 1.0366x; 1.0366x over previous
//
#include <hip/hip_runtime.h>
#include <stdint.h>

#define LOG2E 1.4426950408889634f

typedef __attribute__((ext_vector_type(8))) __bf16 bf16x8;
typedef __attribute__((ext_vector_type(4))) __bf16 bf16x4;
typedef __attribute__((ext_vector_type(4))) float f32x4;

__device__ inline void gll16(const void* g, void* l) {
  __builtin_amdgcn_global_load_lds(
      (const __attribute__((address_space(1))) void*)g,
      (__attribute__((address_space(3))) void*)l, 16, 0, 0);
}

// ---------------- fp32 -> bf16 conversion (all 5 tensors, one launch) ----------------
__global__ __launch_bounds__(256) void cvt_all(
    const float* __restrict__ hs, const float* __restrict__ wq,
    const float* __restrict__ wk, const float* __restrict__ wv,
    const float* __restrict__ wo,
    __bf16* __restrict__ hsb, __bf16* __restrict__ wqb, __bf16* __restrict__ wkb,
    __bf16* __restrict__ wvb, __bf16* __restrict__ wob) {
  int bid = blockIdx.x;
  const float* s; __bf16* d; int i;
  if (bid < 4096) { s = hs; d = hsb; i = bid * 256 + threadIdx.x; }
  else {
    int seg = (bid - 4096) >> 10;
    i = ((bid - 4096) & 1023) * 256 + threadIdx.x;
    s = seg == 0 ? wq : seg == 1 ? wk : seg == 2 ? wv : wo;
    d = seg == 0 ? wqb : seg == 1 ? wkb : seg == 2 ? wvb : wob;
  }
  float4 v = ((const float4*)s)[i];
  bf16x4 o;
  o[0] = (__bf16)v.x; o[1] = (__bf16)v.y; o[2] = (__bf16)v.z; o[3] = (__bf16)v.w;
  *(bf16x4*)&d[(size_t)i * 4] = o;
}

// ---------------- merged QKV projection GEMM ----------------
#define KSCALE 0.18033688011112042f  // HD^-0.5 * log2(e)
__global__ __launch_bounds__(256, 3) void qkv_gemm(
    const __bf16* __restrict__ hsb, const __bf16* __restrict__ wqb,
    const __bf16* __restrict__ wkb, const __bf16* __restrict__ wvb,
    __bf16* __restrict__ qbuf, __bf16* __restrict__ kbuf,
    __bf16* __restrict__ vtb) {
  constexpr int K = 1024;
  __shared__ __align__(16) __bf16 lta[128 * 32];
  __shared__ __align__(16) __bf16 ltb[128 * 32];
  const int bid = blockIdx.x;
  const int z = bid >> 8, r = bid & 255;
  const __bf16 *A, *Bt;
  int m0, n0;
  if (z < 2) {
    A = hsb; Bt = z ? wkb : wqb;
    m0 = (r & 31) * 128; n0 = (r >> 5) * 128;
  } else {
    A = wvb; Bt = hsb;
    m0 = (r & 7) * 128; n0 = (r >> 3) * 128;
  }
  const int tid = threadIdx.x;
  const int w = tid >> 6, l = tid & 63;
  const int lg = l >> 4, lr = l & 15;
  const int wm = (w >> 1) * 64, wn = (w & 1) * 64;
  f32x4 acc[4][4] = {};
  const int srow = w * 16 + (l >> 2);
  const int scol = (l & 3) * 8;
  const __bf16* ga = A + (size_t)(m0 + srow) * K + scol;
  const __bf16* gb = Bt + (size_t)(n0 + srow) * K + scol;
  __bf16* la = &lta[(size_t)w * 16 * 32];
  __bf16* lb = &ltb[(size_t)w * 16 * 32];
  for (int k0 = 0; k0 < K; k0 += 32) {
    __syncthreads();
    gll16(ga + k0, la);
    gll16(ga + 64 * K + k0, la + 64 * 32);
    gll16(gb + k0, lb);
    gll16(gb + 64 * K + k0, lb + 64 * 32);
    __syncthreads();
    bf16x8 af[4], bfr[4];
#pragma unroll
    for (int i = 0; i < 4; ++i) {
      af[i]  = *(const bf16x8*)&lta[(wm + i * 16 + lr) * 32 + lg * 8];
      bfr[i] = *(const bf16x8*)&ltb[(wn + i * 16 + lr) * 32 + lg * 8];
    }
#pragma unroll
    for (int i = 0; i < 4; ++i)
#pragma unroll
      for (int j = 0; j < 4; ++j)
        acc[i][j] = __builtin_amdgcn_mfma_f32_16x16x32_bf16(af[i], bfr[j], acc[i][j], 0, 0, 0);
  }
#pragma unroll
  for (int i = 0; i < 4; ++i)
#pragma unroll
    for (int j = 0; j < 4; ++j)
#pragma unroll
      for (int rr = 0; rr < 4; ++rr) {
        int gm = m0 + wm + i * 16 + lg * 4 + rr;
        int gn = n0 + wn + j * 16 + lr;
        float v = acc[i][j][rr];
        if (z < 2) {
          int bb = gm >> 11, s = gm & 2047, hh = gn >> 6, d = gn & 63;
          __bf16* dst = z ? kbuf : qbuf;
          if (z) v *= KSCALE;
          dst[(((size_t)bb * 16 + hh) * 2048 + s) * 64 + d] = (__bf16)v;
        } else {
          int bb = gn >> 11, s = gn & 2047, hh = gm >> 6, d = gm & 63;
          vtb[(((size_t)bb * 16 + hh) * 64 + d) * 2048 + s] = (__bf16)v;
        }
      }
}

// ---------------- output GEMM: 128x64 tiles -> 512 blocks (2/CU) ----------------
__global__ __launch_bounds__(256, 2) void gemm_out(const __bf16* __restrict__ A,
                                                   const __bf16* __restrict__ Bt,
                                                   float* __restrict__ C,
                                                   int M, int N) {
  constexpr int K = 1024;
  __shared__ __align__(16) __bf16 lta[128 * 32];
  __shared__ __align__(16) __bf16 ltb[64 * 32];
  const int tid = threadIdx.x;
  const int w = tid >> 6, l = tid & 63;
  const int lg = l >> 4, lr = l & 15;
  const int m0 = blockIdx.x * 128, n0 = blockIdx.y * 64;
  const int wm = (w >> 1) * 64, wn = (w & 1) * 32;
  f32x4 acc[4][2] = {};
  const int srow = tid >> 2;          // 0..63
  const int scol = (tid & 3) * 8;
  const __bf16* ga = A + (size_t)(m0 + srow) * K + scol;
  const __bf16* gb = Bt + (size_t)(n0 + srow) * K + scol;
  __bf16* la = &lta[(size_t)w * 512];
  __bf16* lb = &ltb[(size_t)w * 512];
  for (int k0 = 0; k0 < K; k0 += 32) {
    __syncthreads();
    gll16(ga + k0, la);
    gll16(ga + (size_t)64 * K + k0, la + 64 * 32);
    gll16(gb + k0, lb);
    __syncthreads();
    bf16x8 af[4], bfr[2];
#pragma unroll
    for (int i = 0; i < 4; ++i)
      af[i]  = *(const bf16x8*)&lta[(wm + i * 16 + lr) * 32 + lg * 8];
#pragma unroll
    for (int j = 0; j < 2; ++j)
      bfr[j] = *(const bf16x8*)&ltb[(wn + j * 16 + lr) * 32 + lg * 8];
#pragma unroll
    for (int i = 0; i < 4; ++i)
#pragma unroll
      for (int j = 0; j < 2; ++j)
        acc[i][j] = __builtin_amdgcn_mfma_f32_16x16x32_bf16(af[i], bfr[j], acc[i][j], 0, 0, 0);
  }
#pragma unroll
  for (int i = 0; i < 4; ++i)
#pragma unroll
    for (int j = 0; j < 2; ++j)
#pragma unroll
      for (int rr = 0; rr < 4; ++rr) {
        int gm = m0 + wm + i * 16 + lg * 4 + rr;
        int gn = n0 + wn + j * 16 + lr;
        C[(size_t)gm * N + gn] = acc[i][j][rr];
      }
}

// ---------------- attention + memory retrieval ----------------
// 512 blocks; tt = bx>>5, t = tt<8 ? 15-tt : tt-8 (so blocks bx and bx+256
// pair to exactly 17 KV-iters on one CU), bh = bx&31. 128-row q-tiles:
// 4 waves x 32 rows (mf=2 sub-blocks of 16). Swapped QK^T, per-lane q=lr
// softmax in exp2 domain (K pre-scaled). XOR-swizzled LDS; K/V staged via
// global_load_lds with PRE-SWIZZLED global source (linear LDS dest).
#define DEFER_THR 11.5f
#define SWZ(row, col) (((row) << 7) + ((col) ^ (((row) & 7) << 3)))   // stride 128
#define SWZK(row, col) (((row) << 6) + ((col) ^ (((row) & 7) << 3)))  // stride 64

__global__ __launch_bounds__(256, 2) void attn_kernel(
    const __bf16* __restrict__ qb,    // [32][2048][64]
    const __bf16* __restrict__ kb,    // [32][2048][64] (pre-scaled)
    const __bf16* __restrict__ vtb,   // [32][64][2048]
    const float* __restrict__ memory, // [16][64][64]
    const float* __restrict__ memnorm,// [16][64]
    const float* __restrict__ beta,   // [16]
    __bf16* __restrict__ comb)        // [4096][1024]
{
  __shared__ __align__(16) __bf16 kt[128 * 64];   // 16 KB (reused as mt)
  __shared__ __align__(16) __bf16 vt[64 * 128];   // 16 KB
  __shared__ __align__(16) __bf16 pt[4][16 * 128];// 16 KB  -> 48 KB total

  const int tid = threadIdx.x;
  const int w = tid >> 6, l = tid & 63;
  const int lg = l >> 4, lr = l & 15;
  const int tt = blockIdx.x >> 5;
  const int t = (tt < 8) ? (15 - tt) : (tt - 8);
  const int bh = blockIdx.x & 31;
  const int hh = bh & 15, b = bh >> 4;
  const int wq0 = t * 128 + w * 32;
  const int ntiles = t + 1;

  // staging: pre-swizzled global source columns, linear LDS dest.
  // kt chunk c=i*256+tid: row=i*32+(tid>>3), holds global col8 = (tid&7)^(row&7)
  const int k_row = tid >> 3;                          // 0..31
  const int k_col = ((tid & 7) ^ (k_row & 7)) * 8;
  const __bf16* ksrc = kb + ((size_t)bh * 2048 + k_row) * 64 + k_col;
  // vt chunk c=i*256+tid: d=i*16+(tid>>4), holds global col16 = (tid&15)^(d&7)
  const int v_d = tid >> 4;                            // 0..15
  const int v_col = ((tid & 15) ^ (v_d & 7)) * 8;
  const __bf16* vsrc = vtb + ((size_t)bh * 64 + v_d) * 2048 + v_col;
  __bf16* kdst = &kt[w * 512];
  __bf16* vdst = &vt[w * 512];

  // ---- Q fragments (per-lane: row/col = lr; mf picks 16-row sub-block) ----
  bf16x8 qf[2][2];
#pragma unroll
  for (int mf = 0; mf < 2; ++mf)
#pragma unroll
    for (int kk = 0; kk < 2; ++kk)
      qf[mf][kk] = *(const bf16x8*)(qb + ((size_t)bh * 2048 + wq0 + mf * 16 + lr) * 64 + kk * 32 + lg * 8);

  float mrun[2] = {-1e30f, -1e30f}, lsum[2] = {0.f, 0.f};
  f32x4 apv[2][4] = {};

  for (int kv = 0; kv < ntiles; ++kv) {
    const int kv0 = kv * 128;
    __syncthreads();
#pragma unroll
    for (int i = 0; i < 4; ++i) {
      gll16(ksrc + (size_t)(kv0 + i * 32) * 64, kdst + i * 2048);
      gll16(vsrc + (size_t)i * 16 * 2048 + kv0, vdst + i * 2048);
    }
    __syncthreads();   // drains vmcnt before barrier -> tiles ready

    // ---- QK^T swapped: sc[mf][nf]: k = kv0+nf*16+lg*4+r, q = wq0+mf*16+lr ----
    f32x4 sc[2][8] = {};
#pragma unroll
    for (int kk = 0; kk < 2; ++kk)
#pragma unroll
      for (int nf = 0; nf < 8; ++nf) {
        bf16x8 kf = *(const bf16x8*)&kt[SWZK(nf * 16 + lr, kk * 32 + lg * 8)];
#pragma unroll
        for (int mf = 0; mf < 2; ++mf)
          sc[mf][nf] = __builtin_amdgcn_mfma_f32_16x16x32_bf16(kf, qf[mf][kk], sc[mf][nf], 0, 0, 0);
      }

    // ---- causal mask (only last KV tile can overlap) ----
    if (kv == ntiles - 1) {
#pragma unroll
      for (int mf = 0; mf < 2; ++mf) {
        const int qrow = wq0 + mf * 16 + lr;
#pragma unroll
        for (int nf = 0; nf < 8; ++nf)
#pragma unroll
          for (int r = 0; r < 4; ++r)
            if (kv0 + nf * 16 + lg * 4 + r > qrow) sc[mf][nf][r] = -1e30f;
      }
    }

    // ---- per-mf max + defer rescale ----
#pragma unroll
    for (int mf = 0; mf < 2; ++mf) {
      f32x4 m4 = sc[mf][0];
#pragma unroll
      for (int nf = 1; nf < 8; ++nf)
#pragma unroll
        for (int r = 0; r < 4; ++r) m4[r] = fmaxf(m4[r], sc[mf][nf][r]);
      float mx = fmaxf(fmaxf(m4[0], m4[1]), fmaxf(m4[2], m4[3]));
      mx = fmaxf(mx, __shfl_xor(mx, 16, 64));
      mx = fmaxf(mx, __shfl_xor(mx, 32, 64));
      if (!__all(mx - mrun[mf] <= DEFER_THR)) {
        float mold = mrun[mf];
        float mn = fmaxf(mold, mx);
        mrun[mf] = mn;
        float scl = __builtin_amdgcn_exp2f(mold - mn);
        lsum[mf] *= scl;
        float sclq[4];
#pragma unroll
        for (int r = 0; r < 4; ++r) sclq[r] = __shfl(scl, (lg << 2) | r, 16);
#pragma unroll
        for (int nf = 0; nf < 4; ++nf)
#pragma unroll
          for (int r = 0; r < 4; ++r) apv[mf][nf][r] *= sclq[r];
      }
    }

    // ---- P(mf=0) -> pt, cache pa0 in regs; then P(mf=1) -> pt ----
    bf16x8 pa0[4];
    {
      float rs = 0.f;
#pragma unroll
      for (int nf = 0; nf < 8; ++nf) {
        bf16x4 pk;
#pragma unroll
        for (int r = 0; r < 4; ++r) {
          float pv = __builtin_amdgcn_exp2f(sc[0][nf][r] - mrun[0]);
          rs += pv;
          pk[r] = (__bf16)pv;
        }
        *(bf16x4*)&pt[w][SWZ(lr, nf * 16 + lg * 4)] = pk;
      }
      rs += __shfl_xor(rs, 16, 64);
      rs += __shfl_xor(rs, 32, 64);
      lsum[0] += rs;
#pragma unroll
      for (int kk = 0; kk < 4; ++kk)
        pa0[kk] = *(const bf16x8*)&pt[w][SWZ(lr, kk * 32 + lg * 8)];
    }
    {
      float rs = 0.f;
#pragma unroll
      for (int nf = 0; nf < 8; ++nf) {
        bf16x4 pk;
#pragma unroll
        for (int r = 0; r < 4; ++r) {
          float pv = __builtin_amdgcn_exp2f(sc[1][nf][r] - mrun[1]);
          rs += pv;
          pk[r] = (__bf16)pv;
        }
        *(bf16x4*)&pt[w][SWZ(lr, nf * 16 + lg * 4)] = pk;
      }
      rs += __shfl_xor(rs, 16, 64);
      rs += __shfl_xor(rs, 32, 64);
      lsum[1] += rs;
    }

    // ---- PV: V-frags read once, feed both mf ----
#pragma unroll
    for (int kk = 0; kk < 4; ++kk) {
      bf16x8 pa1 = *(const bf16x8*)&pt[w][SWZ(lr, kk * 32 + lg * 8)];
#pragma unroll
      for (int nf = 0; nf < 4; ++nf) {
        bf16x8 vf = *(const bf16x8*)&vt[SWZ(nf * 16 + lr, kk * 32 + lg * 8)];
        apv[0][nf] = __builtin_amdgcn_mfma_f32_16x16x32_bf16(pa0[kk], vf, apv[0][nf], 0, 0, 0);
        apv[1][nf] = __builtin_amdgcn_mfma_f32_16x16x32_bf16(pa1, vf, apv[1][nf], 0, 0, 0);
      }
    }
  }

  // ---- memory retrieval: sigma(Q) @ [M^T | mn replicated] via MFMA ----
  __syncthreads();  // all waves done with kt (QK^T) reads
  __bf16* mt = kt;  // reuse kt region for memory^T [80][72]
  for (int i = tid; i < 64 * 64; i += 256) {
    int d = i >> 6, e = i & 63;
    mt[e * 72 + d] = (__bf16)memory[((size_t)hh * 64 + d) * 64 + e];
  }
  for (int i = tid; i < 16 * 64; i += 256) {
    int e = 64 + (i >> 6), d = i & 63;
    mt[e * 72 + d] = (__bf16)memnorm[hh * 64 + d];
  }
  __syncthreads();

  bf16x8 sf[2][2];
#pragma unroll
  for (int mf = 0; mf < 2; ++mf)
#pragma unroll
    for (int kk = 0; kk < 2; ++kk) {
      bf16x8 q = qf[mf][kk], s;
#pragma unroll
      for (int j = 0; j < 8; ++j) {
        float x = (float)q[j];
        float sg = x > 0.f ? x + 1.f : __builtin_amdgcn_exp2f(x * LOG2E);
        s[j] = (__bf16)sg;
      }
      sf[mf][kk] = s;
    }

  f32x4 am[2][5] = {};
#pragma unroll
  for (int kk = 0; kk < 2; ++kk)
#pragma unroll
    for (int nf = 0; nf < 5; ++nf) {
      bf16x8 bb = *(const bf16x8*)&mt[(nf * 16 + lr) * 72 + kk * 32 + lg * 8];
#pragma unroll
      for (int mf = 0; mf < 2; ++mf)
        am[mf][nf] = __builtin_amdgcn_mfma_f32_16x16x32_bf16(sf[mf][kk], bb, am[mf][nf], 0, 0, 0);
    }

  // ---- combine + write ----
  const float gate = 1.f / (1.f + __builtin_amdgcn_exp2f(-beta[hh] * LOG2E));
  const float og = 1.f - gate;
#pragma unroll
  for (int mf = 0; mf < 2; ++mf) {
    float lsq[4];
#pragma unroll
    for (int r = 0; r < 4; ++r) lsq[r] = __shfl(lsum[mf], (lg << 2) | r, 16);
#pragma unroll
    for (int r = 0; r < 4; ++r) {
      int row = wq0 + mf * 16 + lg * 4 + r;
      float linv = __builtin_amdgcn_rcpf(lsq[r]);
      float nrm = fmaxf(am[mf][4][r], 1e-6f);
      float ninv = __builtin_amdgcn_rcpf(nrm);
      size_t base = ((size_t)b * 2048 + row) * 1024 + hh * 64;
#pragma unroll
      for (int nf = 0; nf < 4; ++nf)
        comb[base + nf * 16 + lr] =
            (__bf16)(gate * am[mf][nf][r] * ninv + og * apv[mf][nf][r] * linv);
    }
  }
}

// ---------------- launch ----------------
extern "C" void kernel_launch(void* const* d_in, const int* in_sizes, int n_in,
                              void* d_out, int out_size, void* d_ws, size_t ws_size,
                              hipStream_t stream) {
  const float* hs      = (const float*)d_in[0];
  const float* wq      = (const float*)d_in[1];
  const float* wk      = (const float*)d_in[2];
  const float* wv      = (const float*)d_in[3];
  const float* wo      = (const float*)d_in[4];
  const float* beta    = (const float*)d_in[5];
  const float* memory  = (const float*)d_in[6];
  const float* memnorm = (const float*)d_in[7];
  float* out = (float*)d_out;

  char* ws = (char*)d_ws;
  __bf16* hsb  = (__bf16*)(ws);                        // 8 MB  [4096][1024]
  __bf16* wqb  = (__bf16*)(ws + ((size_t)8  << 20));   // 2 MB
  __bf16* wkb  = (__bf16*)(ws + ((size_t)10 << 20));   // 2 MB
  __bf16* wvb  = (__bf16*)(ws + ((size_t)12 << 20));   // 2 MB
  __bf16* wob  = (__bf16*)(ws + ((size_t)14 << 20));   // 2 MB
  __bf16* qbuf = (__bf16*)(ws + ((size_t)16 << 20));   // 8 MB  [32][2048][64]
  __bf16* kbuf = (__bf16*)(ws + ((size_t)24 << 20));   // 8 MB
  __bf16* vtb  = (__bf16*)(ws + ((size_t)32 << 20));   // 8 MB  [32][64][2048]
  __bf16* comb = (__bf16*)(ws + ((size_t)40 << 20));   // 8 MB  [4096][1024]

  cvt_all<<<8192, 256, 0, stream>>>(hs, wq, wk, wv, wo, hsb, wqb, wkb, wvb, wob);

  qkv_gemm<<<768, 256, 0, stream>>>(hsb, wqb, wkb, wvb, qbuf, kbuf, vtb);

  attn_kernel<<<512, 256, 0, stream>>>(qbuf, kbuf, vtb, memory, memnorm, beta, comb);

  gemm_out<<<dim3(32, 16), 256, 0, stream>>>(comb, wob, out, 4096, 1024);
}